// Round 2
// baseline (172.596 us; speedup 1.0000x reference)
//
#include <hip/hip_runtime.h>
#include <float.h>
#include <math.h>

#define BATCH 8
#define NPTS 4096
#define KNN 10
#define BN (BATCH * NPTS)          // 32768 points per cloud
#define TPB 1024                   // 16 waves
#define WAVES 16                   // scan segments, one per wave (wave-uniform LDS reads)
#define Q 4                        // queries per lane: 4 insert chains per LDS broadcast
#define QPB (64 * Q)               // 256 queries per block
#define SEGC (NPTS / WAVES)        // 256 candidates per wave
#define KB_STRIDE (Q * KNN + 1)    // 41: odd stride -> 2-way banks (free)

// module-scope normals buffer (1 MiB): avoids any assumption about ws_size
__device__ float4 g_nrm[2 * BN];

__device__ inline float med3f(float x, float a, float b) {
    return __builtin_amdgcn_fmed3f(x, a, b);
}

// branchless sorted insert of key into ascending k[0..9] (drop largest);
// all 9 med3 read pre-insert values -> mutually independent
#define INSERT(karr, key)                                              \
    do {                                                               \
        _Pragma("unroll")                                              \
        for (int _j = KNN - 1; _j >= 1; --_j)                          \
            karr[_j] = med3f((key), karr[_j - 1], karr[_j]);           \
        karr[0] = fminf((key), karr[0]);                               \
    } while (0)

// distance + pack + 4 inserts for one candidate float4 _p at index _gi
#define PROC(_p, _gi)                                                  \
    do {                                                               \
        float _d0 = fmaf((_p).z, a0z, fmaf((_p).y, a0y, fmaf((_p).x, a0x, (_p).w))); \
        float _d1 = fmaf((_p).z, a1z, fmaf((_p).y, a1y, fmaf((_p).x, a1x, (_p).w))); \
        float _d2 = fmaf((_p).z, a2z, fmaf((_p).y, a2y, fmaf((_p).x, a2x, (_p).w))); \
        float _d3 = fmaf((_p).z, a3z, fmaf((_p).y, a3y, fmaf((_p).x, a3x, (_p).w))); \
        float _k0 = __uint_as_float((__float_as_uint(_d0) & 0xFFFFF000u) | (_gi)); \
        float _k1 = __uint_as_float((__float_as_uint(_d1) & 0xFFFFF000u) | (_gi)); \
        float _k2 = __uint_as_float((__float_as_uint(_d2) & 0xFFFFF000u) | (_gi)); \
        float _k3 = __uint_as_float((__float_as_uint(_d3) & 0xFFFFF000u) | (_gi)); \
        INSERT(kq0, _k0);                                              \
        INSERT(kq1, _k1);                                              \
        INSERT(kq2, _k2);                                              \
        INSERT(kq3, _k3);                                              \
    } while (0)

#define PROC4(P, _gi)                                                  \
    do {                                                               \
        PROC(P##0, (_gi) + 0);                                         \
        PROC(P##1, (_gi) + 1);                                         \
        PROC(P##2, (_gi) + 2);                                         \
        PROC(P##3, (_gi) + 3);                                         \
    } while (0)

#define LOAD4(P, _off)                                                 \
    do {                                                               \
        P##0 = pts[(_off) + 0]; P##1 = pts[(_off) + 1];                \
        P##2 = pts[(_off) + 2]; P##3 = pts[(_off) + 3];                \
    } while (0)

// Eigenvector of smallest eigenvalue of symmetric 3x3
__device__ inline void smallest_eigvec(float a00, float a01, float a02,
                                       float a11, float a12, float a22,
                                       float& vx, float& vy, float& vz) {
    float p1 = a01 * a01 + a02 * a02 + a12 * a12;
    float q = (a00 + a11 + a22) * (1.0f / 3.0f);
    float b00 = a00 - q, b11 = a11 - q, b22 = a22 - q;
    float p2 = b00 * b00 + b11 * b11 + b22 * b22 + 2.0f * p1;
    float p = sqrtf(p2 * (1.0f / 6.0f));
    if (p < 1e-20f) { vx = 1.0f; vy = 0.0f; vz = 0.0f; return; }
    float ip = 1.0f / p;
    float c00 = b00 * ip, c01 = a01 * ip, c02 = a02 * ip;
    float c11 = b11 * ip, c12 = a12 * ip, c22 = b22 * ip;
    float detB = c00 * (c11 * c22 - c12 * c12)
               - c01 * (c01 * c22 - c12 * c02)
               + c02 * (c01 * c12 - c11 * c02);
    float r = 0.5f * detB;
    r = fminf(1.0f, fmaxf(-1.0f, r));
    float phi = acosf(r) * (1.0f / 3.0f);
    float lmin = q + 2.0f * p * cosf(phi + 2.0943951023931953f);

    float m00 = a00 - lmin, m11 = a11 - lmin, m22 = a22 - lmin;
    float r0x = m00, r0y = a01, r0z = a02;
    float r1x = a01, r1y = m11, r1z = a12;
    float r2x = a02, r2y = a12, r2z = m22;
    float c0x = r0y * r1z - r0z * r1y, c0y = r0z * r1x - r0x * r1z, c0z = r0x * r1y - r0y * r1x;
    float c1x = r0y * r2z - r0z * r2y, c1y = r0z * r2x - r0x * r2z, c1z = r0x * r2y - r0y * r2x;
    float c2x = r1y * r2z - r1z * r2y, c2y = r1z * r2x - r1x * r2z, c2z = r1x * r2y - r1y * r2x;
    float n0 = c0x * c0x + c0y * c0y + c0z * c0z;
    float n1 = c1x * c1x + c1y * c1y + c1z * c1z;
    float n2 = c2x * c2x + c2y * c2y + c2z * c2z;
    float bx = c0x, by = c0y, bz = c0z, bnm = n0;
    if (n1 > bnm) { bx = c1x; by = c1y; bz = c1z; bnm = n1; }
    if (n2 > bnm) { bx = c2x; by = c2y; bz = c2z; bnm = n2; }
    if (bnm < 1e-30f) { vx = 1.0f; vy = 0.0f; vz = 0.0f; return; }
    float inv = rsqrtf(bnm);
    vx = bx * inv; vy = by * inv; vz = bz * inv;
}

__global__ void zero_out_kernel(float* __restrict__ out) {
    if (threadIdx.x == 0) out[0] = 0.0f;
}

// One block = 256 queries of ONE cloud (blockIdx.z selects pred/gt) of one batch.
// 16 waves (TPB=1024, 1 block/CU); lane l owns queries qbase + l + {0,64,128,192};
// wave w scans segment w (256 candidates) of the staged cloud; tree merge 16->1;
// normals written to g_nrm, loss computed by a second kernel.
__global__ __launch_bounds__(TPB, 4) void knn_normals(
    const float* __restrict__ pred, const float* __restrict__ gt) {
    __shared__ float4 pts[NPTS + 8];                 // 64 KiB + prefetch pad
    __shared__ float keybuf[8 * 64 * KB_STRIDE];     // 84 KB merge buffer (no aliasing)

    const int b = blockIdx.y;
    const int cloud = blockIdx.z;
    const float* __restrict__ base = (cloud ? gt : pred) + b * 3 * NPTS;
    const int tid = threadIdx.x;
    const int lane = tid & 63;
    const int w = tid >> 6;           // wave id = segment id (0..15)
    const int s0 = w * SEGC;          // wave-uniform segment offset
    const int qbase = blockIdx.x * QPB;

    // stage cloud (x, y, z, |p|^2)
    for (int i = tid; i < NPTS; i += TPB) {
        float x = base[i];
        float y = base[NPTS + i];
        float z = base[2 * NPTS + i];
        pts[i] = make_float4(x, y, z, fmaf(x, x, fmaf(y, y, z * z)));
    }
    __syncthreads();

    // query coefficients from staged LDS (queries are in this cloud)
    const int q0 = qbase + lane;
    const float a0x = -2.0f * pts[q0].x,       a0y = -2.0f * pts[q0].y,       a0z = -2.0f * pts[q0].z;
    const float a1x = -2.0f * pts[q0 + 64].x,  a1y = -2.0f * pts[q0 + 64].y,  a1z = -2.0f * pts[q0 + 64].z;
    const float a2x = -2.0f * pts[q0 + 128].x, a2y = -2.0f * pts[q0 + 128].y, a2z = -2.0f * pts[q0 + 128].z;
    const float a3x = -2.0f * pts[q0 + 192].x, a3y = -2.0f * pts[q0 + 192].y, a3z = -2.0f * pts[q0 + 192].z;

    float kq0[KNN], kq1[KNN], kq2[KNN], kq3[KNN];
#pragma unroll
    for (int j = 0; j < KNN; ++j) { kq0[j] = FLT_MAX; kq1[j] = FLT_MAX; kq2[j] = FLT_MAX; kq3[j] = FLT_MAX; }

    // scan: register double-buffer 4+4 float4, sched_barrier fenced; each
    // ds_read_b128 broadcast feeds 4 insert chains (~240 VALU cycles)
    {
        const unsigned gb = (unsigned)s0;
        float4 A0, A1, A2, A3;
        float4 B0, B1, B2, B3;
        LOAD4(A, s0);
        __builtin_amdgcn_sched_barrier(0);
        for (int c = 0; c < SEGC; c += 8) {
            LOAD4(B, s0 + c + 4);
            __builtin_amdgcn_sched_barrier(0);
            PROC4(A, gb + (unsigned)c);
            __builtin_amdgcn_sched_barrier(0);
            LOAD4(A, s0 + c + 8);     /* last iter reads pad */
            __builtin_amdgcn_sched_barrier(0);
            PROC4(B, gb + (unsigned)c + 4u);
            __builtin_amdgcn_sched_barrier(0);
        }
    }

    // tree merge 16->8->4->2->1 (keybuf is its own region; no pre-sync needed)
    for (int half = WAVES / 2; half >= 1; half >>= 1) {
        if (w >= half && w < 2 * half) {
            float* dst = keybuf + ((w - half) * 64 + lane) * KB_STRIDE;
#pragma unroll
            for (int j = 0; j < KNN; ++j) {
                dst[j] = kq0[j];
                dst[KNN + j] = kq1[j];
                dst[2 * KNN + j] = kq2[j];
                dst[3 * KNN + j] = kq3[j];
            }
        }
        __syncthreads();
        if (w < half) {
            const float* src = keybuf + (w * 64 + lane) * KB_STRIDE;
#pragma unroll
            for (int j = 0; j < KNN; ++j) {
                float s0v = src[j], s1v = src[KNN + j], s2v = src[2 * KNN + j], s3v = src[3 * KNN + j];
                INSERT(kq0, s0v);
                INSERT(kq1, s1v);
                INSERT(kq2, s2v);
                INSERT(kq3, s3v);
            }
        }
        __syncthreads();
    }

    // spread the tail: wave 0 publishes final top-10s, waves 0..3 each do one query
    if (w == 0) {
        float* dst = keybuf + lane * KB_STRIDE;
#pragma unroll
        for (int j = 0; j < KNN; ++j) {
            dst[j] = kq0[j];
            dst[KNN + j] = kq1[j];
            dst[2 * KNN + j] = kq2[j];
            dst[3 * KNN + j] = kq3[j];
        }
    }
    __syncthreads();
    if (w < Q) {
        const float* src = keybuf + lane * KB_STRIDE + w * KNN;
        float sx = 0.f, sy = 0.f, sz = 0.f;
        float sxx = 0.f, sxy = 0.f, sxz = 0.f;
        float syy = 0.f, syz = 0.f, szz = 0.f;
#pragma unroll
        for (int j = 0; j < KNN; ++j) {
            int idx = (int)(__float_as_uint(src[j]) & 0xFFFu);
            float4 nb = pts[idx];                       // gather from LDS, not HBM
            sx += nb.x; sy += nb.y; sz += nb.z;
            sxx = fmaf(nb.x, nb.x, sxx); sxy = fmaf(nb.x, nb.y, sxy); sxz = fmaf(nb.x, nb.z, sxz);
            syy = fmaf(nb.y, nb.y, syy); syz = fmaf(nb.y, nb.z, syz); szz = fmaf(nb.z, nb.z, szz);
        }
        const float iK = 1.0f / KNN;
        float mx = sx * iK, my = sy * iK, mz = sz * iK;
        float vx, vy, vz;
        smallest_eigvec(sxx * iK - mx * mx, sxy * iK - mx * my,
                        sxz * iK - mx * mz, syy * iK - my * my,
                        syz * iK - my * mz, szz * iK - mz * mz,
                        vx, vy, vz);
        g_nrm[(cloud * BATCH + b) * NPTS + qbase + w * 64 + lane] = make_float4(vx, vy, vz, 0.f);
    }
}

// loss over 32768 point pairs; one wave-sum atomic per 64 lanes
__global__ __launch_bounds__(256) void cos_loss_kernel(float* __restrict__ out) {
    const int i = blockIdx.x * 256 + threadIdx.x;     // grid sized exactly BN
    float4 p = g_nrm[i];
    float4 g = g_nrm[BN + i];
    float dot = p.x * g.x + p.y * g.y + p.z * g.z;
    float npn = sqrtf(p.x * p.x + p.y * p.y + p.z * p.z);
    float ngn = sqrtf(g.x * g.x + g.y * g.y + g.z * g.z);
    float acc = 1.0f - fabsf(dot / fmaxf(npn * ngn, 1e-8f));
    for (int off = 32; off > 0; off >>= 1) acc += __shfl_down(acc, off);
    if ((threadIdx.x & 63) == 0) atomicAdd(out, acc * (1.0f / (float)BN));
}

extern "C" void kernel_launch(void* const* d_in, const int* in_sizes, int n_in,
                              void* d_out, int out_size, void* d_ws, size_t ws_size,
                              hipStream_t stream) {
    const float* pred = (const float*)d_in[0];
    const float* gt = (const float*)d_in[1];
    float* out = (float*)d_out;

    zero_out_kernel<<<1, 64, 0, stream>>>(out);
    dim3 grid(NPTS / QPB, BATCH, 2);  // 16 x 8 x 2 = 256 blocks (1 per CU)
    knn_normals<<<grid, TPB, 0, stream>>>(pred, gt);
    cos_loss_kernel<<<dim3(BN / 256), 256, 0, stream>>>(out);
}